// Round 13
// baseline (180.369 us; speedup 1.0000x reference)
//
#include <hip/hip_runtime.h>
#include <hip/hip_bf16.h>

// Multihead cross-attention, B=2, LQ=LK=4096, D=768, H=8, dh=96.
// Pipeline: prep (W transpose + X f32->bf16, one launch) -> fused QKV proj
// (128^2 tile, glds dbuf, XOR-swizzled LDS) -> flash attn (32x32x16,
// 32q/wave, cross-tile pipeline, no-max softmax, circular K-loop offset to
// phase-desync co-resident blocks, setprio on both MFMA clusters).

typedef __bf16 bf16x8 __attribute__((ext_vector_type(8)));
typedef __bf16 bf16x4 __attribute__((ext_vector_type(4)));
typedef float  f32x4  __attribute__((ext_vector_type(4)));
typedef float  f32x16 __attribute__((ext_vector_type(16)));
typedef unsigned u32x4 __attribute__((ext_vector_type(4)));

#define DM   768
#define NH   8
#define HD   96
#define SEQ  4096
#define BATCH 2
#define WELEM (DM*DM)         // 589824
#define XELEM (BATCH*SEQ*DM)  // 6291456

#define GLDS16(gp, lp) __builtin_amdgcn_global_load_lds( \
    (const __attribute__((address_space(1))) void*)(gp), \
    (__attribute__((address_space(3))) void*)(lp), 16, 0, 0)

// ---------------- prep: X f32->bf16 convert (6144 blocks) + W transpose (432) --
__global__ __launch_bounds__(256) void prep(
    const float* __restrict__ hidden, const float* __restrict__ kv,
    const float* __restrict__ Wq, const float* __restrict__ Wk,
    const float* __restrict__ Wv,
    __bf16* __restrict__ Xh_bf, __bf16* __restrict__ Xkv_bf,
    __bf16* __restrict__ Tq, __bf16* __restrict__ Tk, __bf16* __restrict__ Tv)
{
    __shared__ __bf16 Ls[64][72];   // used by transpose blocks only
    const int id = blockIdx.x;
    const int t = threadIdx.x;

    if (id < 6144) {                // convert: blocks 0..3071 hidden, 3072.. kv
        const int half = id >= 3072;
        const float* X = half ? kv : hidden;
        __bf16* Y      = half ? Xkv_bf : Xh_bf;
        const size_t i = ((size_t)(id - half * 3072) * 256 + t) * 8;
        float4 lo = *reinterpret_cast<const float4*>(X + i);
        float4 hi = *reinterpret_cast<const float4*>(X + i + 4);
        bf16x8 v;
        v[0]=(__bf16)lo.x; v[1]=(__bf16)lo.y; v[2]=(__bf16)lo.z; v[3]=(__bf16)lo.w;
        v[4]=(__bf16)hi.x; v[5]=(__bf16)hi.y; v[6]=(__bf16)hi.z; v[7]=(__bf16)hi.w;
        *reinterpret_cast<bf16x8*>(Y + i) = v;
        return;
    }

    // transpose: 432 blocks = 3 * 144 tiles of 64x64
    const int id2 = id - 6144;
    const int which = id2 / 144;
    const int tile = id2 - which * 144;
    const int ti = tile / 12, tj = tile % 12;
    const float* W = (which == 0) ? Wq : (which == 1) ? Wk : Wv;
    __bf16* T      = (which == 0) ? Tq : (which == 1) ? Tk : Tv;

    const int row = t >> 2, q4 = t & 3;
    const float* src = W + (size_t)(ti * 64 + row) * DM + tj * 64 + q4 * 16;
    float4 f0 = *reinterpret_cast<const float4*>(src);
    float4 f1 = *reinterpret_cast<const float4*>(src + 4);
    float4 f2 = *reinterpret_cast<const float4*>(src + 8);
    float4 f3 = *reinterpret_cast<const float4*>(src + 12);
    bf16x8 v0, v1;
    v0[0]=(__bf16)f0.x; v0[1]=(__bf16)f0.y; v0[2]=(__bf16)f0.z; v0[3]=(__bf16)f0.w;
    v0[4]=(__bf16)f1.x; v0[5]=(__bf16)f1.y; v0[6]=(__bf16)f1.z; v0[7]=(__bf16)f1.w;
    v1[0]=(__bf16)f2.x; v1[1]=(__bf16)f2.y; v1[2]=(__bf16)f2.z; v1[3]=(__bf16)f2.w;
    v1[4]=(__bf16)f3.x; v1[5]=(__bf16)f3.y; v1[6]=(__bf16)f3.z; v1[7]=(__bf16)f3.w;
    *reinterpret_cast<bf16x8*>(&Ls[row][q4 * 16])     = v0;
    *reinterpret_cast<bf16x8*>(&Ls[row][q4 * 16 + 8]) = v1;
    __syncthreads();
    #pragma unroll
    for (int j = 0; j < 2; ++j) {
        const int idx = t + j * 256;
        const int orow = idx >> 3, oc = idx & 7;
        bf16x8 o;
        #pragma unroll
        for (int e = 0; e < 8; ++e) o[e] = Ls[oc * 8 + e][orow];
        *reinterpret_cast<bf16x8*>(
            &T[(size_t)(tj * 64 + orow) * DM + ti * 64 + oc * 8]) = o;
    }
}

// ---------------- fused QKV projection: one launch, 1152 blocks ----------------
__global__ __launch_bounds__(256, 2) void proj_all(
    const __bf16* __restrict__ Xh, const __bf16* __restrict__ Xkv,
    const __bf16* __restrict__ Wtq, const __bf16* __restrict__ Wtk,
    const __bf16* __restrict__ Wtv, __bf16* __restrict__ Yq,
    __bf16* __restrict__ Yk, __bf16* __restrict__ Yv, float qscale)
{
    __shared__ __bf16 As[2][128][64];   // 32 KB
    __shared__ __bf16 Bs[2][128][64];   // 32 KB

    const int t = threadIdx.x;
    const int l = t & 63;
    const int w = t >> 6;
    const int ln = l & 15, g = l >> 4;
    const int wm = w >> 1, wn = w & 1;

    const int id3 = blockIdx.x;
    const int xcd = id3 & 7;
    const int u = id3 >> 3;            // 0..143
    const int which = u % 3;
    const int c = u / 3;               // 0..47
    const int m0 = (xcd * 8 + c / 6) * 128;
    const int n0 = (c % 6) * 128;

    const __bf16* Xb = (which == 0) ? Xh : Xkv;
    const __bf16* Wt = (which == 0) ? Wtq : (which == 1) ? Wtk : Wtv;
    __bf16* Y        = (which == 0) ? Yq : (which == 1) ? Yk : Yv;
    const int mode   = (which == 2) ? 1 : 0;
    const float scale = (which == 0) ? qscale : 1.0f;

    size_t asrc[4], bsrc[4]; unsigned sdst[4];
    #pragma unroll
    for (int j = 0; j < 4; ++j) {
        const int cid = j * 256 + t;              // 0..1023
        const int r = cid >> 3, cc = cid & 7, cs = cc ^ (r & 7);
        asrc[j] = (size_t)(m0 + r) * DM + cs * 8;
        bsrc[j] = (size_t)(n0 + r) * DM + cs * 8;
        sdst[j] = cid * 16;
    }

    f32x4 acc[4][4] = {};

    #pragma unroll
    for (int j = 0; j < 4; ++j) GLDS16(Xb + asrc[j], (char*)As + sdst[j]);
    #pragma unroll
    for (int j = 0; j < 4; ++j) GLDS16(Wt + bsrc[j], (char*)Bs + sdst[j]);
    __syncthreads();

    const int NKT = DM / 64;   // 12
    for (int kt = 0; kt < NKT; ++kt) {
        const int cur = kt & 1;
        if (kt + 1 < NKT) {
            const unsigned nb = (cur ^ 1) * 16384u;
            const size_t k0n = (size_t)(kt + 1) * 64;
            #pragma unroll
            for (int j = 0; j < 4; ++j) GLDS16(Xb + k0n + asrc[j], (char*)As + nb + sdst[j]);
            #pragma unroll
            for (int j = 0; j < 4; ++j) GLDS16(Wt + k0n + bsrc[j], (char*)Bs + nb + sdst[j]);
        }

        #pragma unroll
        for (int kk = 0; kk < 2; ++kk) {
            bf16x8 a[4], b[4];
            #pragma unroll
            for (int ms = 0; ms < 4; ++ms) {
                const int row = wm * 64 + ms * 16 + ln;
                const int slot = (kk * 4 + g) ^ (row & 7);
                a[ms] = *reinterpret_cast<const bf16x8*>(
                    (const char*)As + cur * 16384 + row * 128 + slot * 16);
            }
            #pragma unroll
            for (int ns = 0; ns < 4; ++ns) {
                const int row = wn * 64 + ns * 16 + ln;
                const int slot = (kk * 4 + g) ^ (row & 7);
                b[ns] = *reinterpret_cast<const bf16x8*>(
                    (const char*)Bs + cur * 16384 + row * 128 + slot * 16);
            }
            #pragma unroll
            for (int ms = 0; ms < 4; ++ms)
                #pragma unroll
                for (int ns = 0; ns < 4; ++ns)
                    acc[ms][ns] = __builtin_amdgcn_mfma_f32_16x16x32_bf16(
                        a[ms], b[ns], acc[ms][ns], 0, 0, 0);
        }
        __syncthreads();
    }

    // epilogue: D layout col=ln, row=4g+r  [m89]
    #pragma unroll
    for (int ms = 0; ms < 4; ++ms) {
        #pragma unroll
        for (int ns = 0; ns < 4; ++ns) {
            const int col = n0 + wn * 64 + ns * 16 + ln;
            const int h = col / HD, d = col - h * HD;
            const int row_base = m0 + wm * 64 + ms * 16 + 4 * g;
            if (mode == 0) {
                #pragma unroll
                for (int r = 0; r < 4; ++r) {
                    const int row = row_base + r;
                    const int b_ = row >> 12, q = row & (SEQ - 1);
                    Y[(((size_t)(b_ * NH + h) * SEQ) + q) * HD + d] =
                        (__bf16)(acc[ms][ns][r] * scale);
                }
            } else {
                const int b_ = row_base >> 12, kq = row_base & (SEQ - 1);
                bf16x4 v;
                #pragma unroll
                for (int r = 0; r < 4; ++r) v[r] = (__bf16)acc[ms][ns][r];
                *reinterpret_cast<bf16x4*>(
                    &Y[((size_t)(b_ * NH + h) * HD + d) * SEQ + kq]) = v;
            }
        }
    }
}

// ---------------- flash attention: pipelined, 32x32x16, NO-MAX softmax --------
// 512 blocks (XCD-chunked), 4 waves x 32 q. K dbuf [2][64][128] (XOR r&7),
// V 3-buf [3][96][64] (XOR d&7). p = exp2(s) raw (constant scale cancels in
// sum(p*v)/sum(p)). Odd-qb blocks start the K-loop at tile NT/2 (circular):
// no-max softmax is order-independent, and co-resident blocks desync ->
// one block's MFMA phase overlaps the other's VALU phase.
__global__ __launch_bounds__(256, 2) void attn_kernel(
    const __bf16* __restrict__ Q, const __bf16* __restrict__ K,
    const __bf16* __restrict__ Vt, float* __restrict__ out)
{
    __shared__ __bf16 Ks[2][64][128];  // 32 KB
    __shared__ __bf16 Vs[3][96][64];   // 36 KB

    const int t_ = threadIdx.x;
    const int l = t_ & 63;
    const int w = t_ >> 6;
    const int lh = l >> 5;
    const int c31 = l & 31;

    const int swz = (blockIdx.x & 7) * 64 + (blockIdx.x >> 3);
    const int bh = swz >> 5;          // 0..15
    const int qb = swz & 31;          // 0..31
    const int b = bh >> 3, hd = bh & 7;
    const int q0 = qb * 128 + w * 32;

    const int NT = SEQ / 64;          // 64
    const int t0 = (qb & 1) * (NT / 2);  // circular start: desync co-resident blocks

    const size_t base = (size_t)bh * SEQ * HD;
    const __bf16* Kg = K + base;
    const __bf16* Vg = Vt + base;

    size_t ksrc[4], vsrc[3];
    unsigned kdst[4], vdst[3];
    #pragma unroll
    for (int j = 0; j < 4; ++j) {
        const int cid = (w * 4 + j) * 64 + l;        // 0..1023
        const int r = cid >> 4, cc = cid & 15;
        int cs = cc ^ (r & 7); if (cs >= 12) cs = 0;
        ksrc[j] = (size_t)r * HD + cs * 8;
        kdst[j] = (w * 4 + j) * 1024;
    }
    #pragma unroll
    for (int j = 0; j < 3; ++j) {
        const int cid = (w * 3 + j) * 64 + l;        // 0..767
        const int d = cid >> 3, cc = cid & 7;
        const int cs = cc ^ (d & 7);
        vsrc[j] = (size_t)d * SEQ + cs * 8;
        vdst[j] = (w * 3 + j) * 1024;
    }

    // Q B-fragments (col = q = lane&31, k(d) = 16*st + 8*lh + e)
    bf16x8 qf[6];
    #pragma unroll
    for (int st = 0; st < 6; ++st)
        qf[st] = *reinterpret_cast<const bf16x8*>(
            &Q[base + (size_t)(q0 + c31) * HD + st * 16 + 8 * lh]);

    f32x16 acc[3] = {};
    f32x16 sA0, sA1, sB0, sB1;
    float l_r = 0.f;
    int vcur = 0, vst = 2;

    auto LT = [&](int u) {            // logical tile with circular offset
        int v = t0 + u;
        return v >= NT ? v - NT : v;
    };

    auto STAGE = [&](int tile, int kp, int vbuf) {
        const size_t ko = (size_t)tile * 64 * HD;
        #pragma unroll
        for (int j = 0; j < 4; ++j)
            GLDS16(Kg + ko + ksrc[j], (char*)Ks + kp * 16384 + kdst[j]);
        const size_t vo = (size_t)tile * 64;
        #pragma unroll
        for (int j = 0; j < 3; ++j)
            GLDS16(Vg + vo + vsrc[j], (char*)Vs + vbuf * 12288 + vdst[j]);
    };

    auto QKT = [&](int pbuf, f32x16& S0, f32x16& S1) {
        S0 = (f32x16){}; S1 = (f32x16){};
        __builtin_amdgcn_s_setprio(1);
        #pragma unroll
        for (int st = 0; st < 6; ++st) {
            const int slot = (2 * st + lh) ^ (c31 & 7);
            bf16x8 ka0 = *reinterpret_cast<const bf16x8*>(
                (const char*)Ks + pbuf * 16384 + c31 * 256 + slot * 16);
            bf16x8 ka1 = *reinterpret_cast<const bf16x8*>(
                (const char*)Ks + pbuf * 16384 + (32 + c31) * 256 + slot * 16);
            S0 = __builtin_amdgcn_mfma_f32_32x32x16_bf16(ka0, qf[st], S0, 0, 0, 0);
            S1 = __builtin_amdgcn_mfma_f32_32x32x16_bf16(ka1, qf[st], S1, 0, 0, 0);
        }
        __builtin_amdgcn_s_setprio(0);
    };

    auto SMPV = [&](f32x16& S0, f32x16& S1) {
        float p0 = 0.f, p1 = 0.f;
        #pragma unroll
        for (int r = 0; r < 16; ++r) {
            const float e0 = __builtin_amdgcn_exp2f(S0[r]);
            const float e1 = __builtin_amdgcn_exp2f(S1[r]);
            S0[r] = e0; S1[r] = e1; p0 += e0; p1 += e1;
        }
        l_r += p0 + p1;
        unsigned up[2][4][2];
        #pragma unroll
        for (int qd = 0; qd < 4; ++qd)
            #pragma unroll
            for (int j = 0; j < 2; ++j) {
                asm("v_cvt_pk_bf16_f32 %0, %1, %2"
                    : "=v"(up[0][qd][j])
                    : "v"(S0[4 * qd + 2 * j]), "v"(S0[4 * qd + 2 * j + 1]));
                asm("v_cvt_pk_bf16_f32 %0, %1, %2"
                    : "=v"(up[1][qd][j])
                    : "v"(S1[4 * qd + 2 * j]), "v"(S1[4 * qd + 2 * j + 1]));
            }
        const unsigned vbo = vcur * 12288;
        #pragma unroll
        for (int kc = 0; kc < 4; ++kc) {
            const int ks = kc >> 1, cp = kc & 1;
            unsigned x0 = up[ks][2 * cp][0],     x1 = up[ks][2 * cp][1];
            unsigned y0 = up[ks][2 * cp + 1][0], y1 = up[ks][2 * cp + 1][1];
            asm("v_permlane32_swap_b32 %0, %1" : "+v"(x0), "+v"(y0));
            asm("v_permlane32_swap_b32 %0, %1" : "+v"(x1), "+v"(y1));
            u32x4 pw; pw[0] = x0; pw[1] = x1; pw[2] = y0; pw[3] = y1;
            const bf16x8 pa = __builtin_bit_cast(bf16x8, pw);
            __builtin_amdgcn_s_setprio(1);
            #pragma unroll
            for (int dt = 0; dt < 3; ++dt) {
                const int dd = dt * 32 + c31;
                const int slot = (2 * kc + lh) ^ (dd & 7);
                bf16x8 vb = *reinterpret_cast<const bf16x8*>(
                    (const char*)Vs + vbo + dd * 128 + slot * 16);
                acc[dt] = __builtin_amdgcn_mfma_f32_32x32x16_bf16(pa, vb, acc[dt], 0, 0, 0);
            }
            __builtin_amdgcn_s_setprio(0);
        }
        vcur = (vcur == 2) ? 0 : vcur + 1;
        vst  = (vst  == 2) ? 0 : vst  + 1;
    };

    // prologue
    STAGE(LT(0), 0, 0);
    __syncthreads();
    STAGE(LT(1), 1, 1);
    QKT(0, sA0, sA1);

    for (int u2 = 0; u2 < NT / 2; ++u2) {
        const int u = 2 * u2;
        __syncthreads();                       // stage(u+1) drained; PV(u-1) done
        if (u + 2 < NT) STAGE(LT(u + 2), 0, vst);
        QKT(1, sB0, sB1);
        SMPV(sA0, sA1);
        __syncthreads();
        if (u + 3 < NT) STAGE(LT(u + 3), 1, vst);
        if (u + 2 < NT) QKT(0, sA0, sA1);
        SMPV(sB0, sB1);
    }

    // epilogue: merge l across lane-halves (one permlane), normalize, store
    {
        float ex = l_r;
        asm volatile("" : "+v"(ex));
        asm("v_permlane32_swap_b32 %0, %1" : "+v"(ex), "+v"(l_r));
        l_r += ex;
    }
    const float inv = 1.0f / l_r;
    #pragma unroll
    for (int r = 0; r < 16; ++r) {
        const int ql = (r & 3) + 8 * (r >> 2) + 4 * lh;
        const float ir = __shfl(inv, ql, 64);
        const int q = q0 + ql;
        float* dst = out + ((size_t)(b * SEQ + q)) * DM + hd * HD;
        #pragma unroll
        for (int dt = 0; dt < 3; ++dt)
            dst[dt * 32 + c31] = acc[dt][r] * ir;
    }
}

extern "C" void kernel_launch(void* const* d_in, const int* in_sizes, int n_in,
                              void* d_out, int out_size, void* d_ws, size_t ws_size,
                              hipStream_t stream) {
    const float* hidden = (const float*)d_in[0];
    const float* kv     = (const float*)d_in[1];
    const float* Wq     = (const float*)d_in[2];
    const float* Wk     = (const float*)d_in[3];
    const float* Wv     = (const float*)d_in[4];
    float* out = (float*)d_out;

    // ws layout (bf16): Wt_q, Wt_k, Wt_v, Q, K, Vt  (~41.3 MB total)
    __bf16* Wt_q = (__bf16*)d_ws;
    __bf16* Wt_k = Wt_q + WELEM;
    __bf16* Wt_v = Wt_k + WELEM;
    __bf16* Qb   = Wt_v + WELEM;
    __bf16* Kb   = Qb + XELEM;
    __bf16* Vtb  = Kb + XELEM;

    // converted X lives in d_out (consumed by proj_all, then attn overwrites)
    __bf16* Xh_bf  = (__bf16*)d_out;
    __bf16* Xkv_bf = Xh_bf + XELEM;

    prep<<<6576, 256, 0, stream>>>(hidden, kv, Wq, Wk, Wv,
                                   Xh_bf, Xkv_bf, Wt_q, Wt_k, Wt_v);

    const float qscale = 0.10206207261596575f * 1.4426950408889634f; // 1/sqrt(96)*log2(e)
    proj_all<<<1152, 256, 0, stream>>>(Xh_bf, Xkv_bf, Wt_q, Wt_k, Wt_v,
                                       Qb, Kb, Vtb, qscale);

    attn_kernel<<<512, 256, 0, stream>>>(Qb, Kb, Vtb, out);
}

// Round 14
// 176.401 us; speedup vs baseline: 1.0225x; 1.0225x over previous
//
#include <hip/hip_runtime.h>
#include <hip/hip_bf16.h>

// Multihead cross-attention, B=2, LQ=LK=4096, D=768, H=8, dh=96.
// Pipeline: prep (W transpose + X f32->bf16, one launch) -> fused QKV proj
// (128^2 tile, glds dbuf, XOR-swizzled LDS) -> flash attn (32x32x16,
// 32q/wave, cross-tile pipeline, no-max softmax; per-block-parity phase
// ordering {QKT;SMPV} vs {SMPV;QKT} to interleave MFMA/VALU across the
// two co-resident blocks on each SIMD).

typedef __bf16 bf16x8 __attribute__((ext_vector_type(8)));
typedef __bf16 bf16x4 __attribute__((ext_vector_type(4)));
typedef float  f32x4  __attribute__((ext_vector_type(4)));
typedef float  f32x16 __attribute__((ext_vector_type(16)));
typedef unsigned u32x4 __attribute__((ext_vector_type(4)));

#define DM   768
#define NH   8
#define HD   96
#define SEQ  4096
#define BATCH 2
#define WELEM (DM*DM)         // 589824
#define XELEM (BATCH*SEQ*DM)  // 6291456

#define GLDS16(gp, lp) __builtin_amdgcn_global_load_lds( \
    (const __attribute__((address_space(1))) void*)(gp), \
    (__attribute__((address_space(3))) void*)(lp), 16, 0, 0)

// ---------------- prep: X f32->bf16 convert (6144 blocks) + W transpose (432) --
__global__ __launch_bounds__(256) void prep(
    const float* __restrict__ hidden, const float* __restrict__ kv,
    const float* __restrict__ Wq, const float* __restrict__ Wk,
    const float* __restrict__ Wv,
    __bf16* __restrict__ Xh_bf, __bf16* __restrict__ Xkv_bf,
    __bf16* __restrict__ Tq, __bf16* __restrict__ Tk, __bf16* __restrict__ Tv)
{
    __shared__ __bf16 Ls[64][72];   // used by transpose blocks only
    const int id = blockIdx.x;
    const int t = threadIdx.x;

    if (id < 6144) {                // convert: blocks 0..3071 hidden, 3072.. kv
        const int half = id >= 3072;
        const float* X = half ? kv : hidden;
        __bf16* Y      = half ? Xkv_bf : Xh_bf;
        const size_t i = ((size_t)(id - half * 3072) * 256 + t) * 8;
        float4 lo = *reinterpret_cast<const float4*>(X + i);
        float4 hi = *reinterpret_cast<const float4*>(X + i + 4);
        bf16x8 v;
        v[0]=(__bf16)lo.x; v[1]=(__bf16)lo.y; v[2]=(__bf16)lo.z; v[3]=(__bf16)lo.w;
        v[4]=(__bf16)hi.x; v[5]=(__bf16)hi.y; v[6]=(__bf16)hi.z; v[7]=(__bf16)hi.w;
        *reinterpret_cast<bf16x8*>(Y + i) = v;
        return;
    }

    // transpose: 432 blocks = 3 * 144 tiles of 64x64
    const int id2 = id - 6144;
    const int which = id2 / 144;
    const int tile = id2 - which * 144;
    const int ti = tile / 12, tj = tile % 12;
    const float* W = (which == 0) ? Wq : (which == 1) ? Wk : Wv;
    __bf16* T      = (which == 0) ? Tq : (which == 1) ? Tk : Tv;

    const int row = t >> 2, q4 = t & 3;
    const float* src = W + (size_t)(ti * 64 + row) * DM + tj * 64 + q4 * 16;
    float4 f0 = *reinterpret_cast<const float4*>(src);
    float4 f1 = *reinterpret_cast<const float4*>(src + 4);
    float4 f2 = *reinterpret_cast<const float4*>(src + 8);
    float4 f3 = *reinterpret_cast<const float4*>(src + 12);
    bf16x8 v0, v1;
    v0[0]=(__bf16)f0.x; v0[1]=(__bf16)f0.y; v0[2]=(__bf16)f0.z; v0[3]=(__bf16)f0.w;
    v0[4]=(__bf16)f1.x; v0[5]=(__bf16)f1.y; v0[6]=(__bf16)f1.z; v0[7]=(__bf16)f1.w;
    v1[0]=(__bf16)f2.x; v1[1]=(__bf16)f2.y; v1[2]=(__bf16)f2.z; v1[3]=(__bf16)f2.w;
    v1[4]=(__bf16)f3.x; v1[5]=(__bf16)f3.y; v1[6]=(__bf16)f3.z; v1[7]=(__bf16)f3.w;
    *reinterpret_cast<bf16x8*>(&Ls[row][q4 * 16])     = v0;
    *reinterpret_cast<bf16x8*>(&Ls[row][q4 * 16 + 8]) = v1;
    __syncthreads();
    #pragma unroll
    for (int j = 0; j < 2; ++j) {
        const int idx = t + j * 256;
        const int orow = idx >> 3, oc = idx & 7;
        bf16x8 o;
        #pragma unroll
        for (int e = 0; e < 8; ++e) o[e] = Ls[oc * 8 + e][orow];
        *reinterpret_cast<bf16x8*>(
            &T[(size_t)(tj * 64 + orow) * DM + ti * 64 + oc * 8]) = o;
    }
}

// ---------------- fused QKV projection: one launch, 1152 blocks ----------------
__global__ __launch_bounds__(256, 2) void proj_all(
    const __bf16* __restrict__ Xh, const __bf16* __restrict__ Xkv,
    const __bf16* __restrict__ Wtq, const __bf16* __restrict__ Wtk,
    const __bf16* __restrict__ Wtv, __bf16* __restrict__ Yq,
    __bf16* __restrict__ Yk, __bf16* __restrict__ Yv, float qscale)
{
    __shared__ __bf16 As[2][128][64];   // 32 KB
    __shared__ __bf16 Bs[2][128][64];   // 32 KB

    const int t = threadIdx.x;
    const int l = t & 63;
    const int w = t >> 6;
    const int ln = l & 15, g = l >> 4;
    const int wm = w >> 1, wn = w & 1;

    const int id3 = blockIdx.x;
    const int xcd = id3 & 7;
    const int u = id3 >> 3;            // 0..143
    const int which = u % 3;
    const int c = u / 3;               // 0..47
    const int m0 = (xcd * 8 + c / 6) * 128;
    const int n0 = (c % 6) * 128;

    const __bf16* Xb = (which == 0) ? Xh : Xkv;
    const __bf16* Wt = (which == 0) ? Wtq : (which == 1) ? Wtk : Wtv;
    __bf16* Y        = (which == 0) ? Yq : (which == 1) ? Yk : Yv;
    const int mode   = (which == 2) ? 1 : 0;
    const float scale = (which == 0) ? qscale : 1.0f;

    size_t asrc[4], bsrc[4]; unsigned sdst[4];
    #pragma unroll
    for (int j = 0; j < 4; ++j) {
        const int cid = j * 256 + t;              // 0..1023
        const int r = cid >> 3, cc = cid & 7, cs = cc ^ (r & 7);
        asrc[j] = (size_t)(m0 + r) * DM + cs * 8;
        bsrc[j] = (size_t)(n0 + r) * DM + cs * 8;
        sdst[j] = cid * 16;
    }

    f32x4 acc[4][4] = {};

    #pragma unroll
    for (int j = 0; j < 4; ++j) GLDS16(Xb + asrc[j], (char*)As + sdst[j]);
    #pragma unroll
    for (int j = 0; j < 4; ++j) GLDS16(Wt + bsrc[j], (char*)Bs + sdst[j]);
    __syncthreads();

    const int NKT = DM / 64;   // 12
    for (int kt = 0; kt < NKT; ++kt) {
        const int cur = kt & 1;
        if (kt + 1 < NKT) {
            const unsigned nb = (cur ^ 1) * 16384u;
            const size_t k0n = (size_t)(kt + 1) * 64;
            #pragma unroll
            for (int j = 0; j < 4; ++j) GLDS16(Xb + k0n + asrc[j], (char*)As + nb + sdst[j]);
            #pragma unroll
            for (int j = 0; j < 4; ++j) GLDS16(Wt + k0n + bsrc[j], (char*)Bs + nb + sdst[j]);
        }

        #pragma unroll
        for (int kk = 0; kk < 2; ++kk) {
            bf16x8 a[4], b[4];
            #pragma unroll
            for (int ms = 0; ms < 4; ++ms) {
                const int row = wm * 64 + ms * 16 + ln;
                const int slot = (kk * 4 + g) ^ (row & 7);
                a[ms] = *reinterpret_cast<const bf16x8*>(
                    (const char*)As + cur * 16384 + row * 128 + slot * 16);
            }
            #pragma unroll
            for (int ns = 0; ns < 4; ++ns) {
                const int row = wn * 64 + ns * 16 + ln;
                const int slot = (kk * 4 + g) ^ (row & 7);
                b[ns] = *reinterpret_cast<const bf16x8*>(
                    (const char*)Bs + cur * 16384 + row * 128 + slot * 16);
            }
            #pragma unroll
            for (int ms = 0; ms < 4; ++ms)
                #pragma unroll
                for (int ns = 0; ns < 4; ++ns)
                    acc[ms][ns] = __builtin_amdgcn_mfma_f32_16x16x32_bf16(
                        a[ms], b[ns], acc[ms][ns], 0, 0, 0);
        }
        __syncthreads();
    }

    // epilogue: D layout col=ln, row=4g+r  [m89]
    #pragma unroll
    for (int ms = 0; ms < 4; ++ms) {
        #pragma unroll
        for (int ns = 0; ns < 4; ++ns) {
            const int col = n0 + wn * 64 + ns * 16 + ln;
            const int h = col / HD, d = col - h * HD;
            const int row_base = m0 + wm * 64 + ms * 16 + 4 * g;
            if (mode == 0) {
                #pragma unroll
                for (int r = 0; r < 4; ++r) {
                    const int row = row_base + r;
                    const int b_ = row >> 12, q = row & (SEQ - 1);
                    Y[(((size_t)(b_ * NH + h) * SEQ) + q) * HD + d] =
                        (__bf16)(acc[ms][ns][r] * scale);
                }
            } else {
                const int b_ = row_base >> 12, kq = row_base & (SEQ - 1);
                bf16x4 v;
                #pragma unroll
                for (int r = 0; r < 4; ++r) v[r] = (__bf16)acc[ms][ns][r];
                *reinterpret_cast<bf16x4*>(
                    &Y[((size_t)(b_ * NH + h) * HD + d) * SEQ + kq]) = v;
            }
        }
    }
}

// ---------------- flash attention: pipelined, 32x32x16, NO-MAX softmax --------
// 512 blocks (XCD-chunked), 4 waves x 32 q. K dbuf [2][64][128] (XOR r&7),
// V 3-buf [3][96][64] (XOR d&7). p = exp2(s) raw.
// Per-block-parity phase order: even blocks {QKT; SMPV}, odd {SMPV; QKT} —
// the two phases are independent, so co-resident blocks on a SIMD overlap
// one's MFMA/LDS phase with the other's VALU phase.
__global__ __launch_bounds__(256, 2) void attn_kernel(
    const __bf16* __restrict__ Q, const __bf16* __restrict__ K,
    const __bf16* __restrict__ Vt, float* __restrict__ out)
{
    __shared__ __bf16 Ks[2][64][128];  // 32 KB
    __shared__ __bf16 Vs[3][96][64];   // 36 KB

    const int t_ = threadIdx.x;
    const int l = t_ & 63;
    const int w = t_ >> 6;
    const int lh = l >> 5;
    const int c31 = l & 31;

    const int swz = (blockIdx.x & 7) * 64 + (blockIdx.x >> 3);
    const int bh = swz >> 5;          // 0..15
    const int qb = swz & 31;          // 0..31
    const int b = bh >> 3, hd = bh & 7;
    const int q0 = qb * 128 + w * 32;
    const int ord = (blockIdx.x >> 8) & 1;   // co-resident pair (c, c+256) differ

    const size_t base = (size_t)bh * SEQ * HD;
    const __bf16* Kg = K + base;
    const __bf16* Vg = Vt + base;

    size_t ksrc[4], vsrc[3];
    unsigned kdst[4], vdst[3];
    #pragma unroll
    for (int j = 0; j < 4; ++j) {
        const int cid = (w * 4 + j) * 64 + l;        // 0..1023
        const int r = cid >> 4, cc = cid & 15;
        int cs = cc ^ (r & 7); if (cs >= 12) cs = 0;
        ksrc[j] = (size_t)r * HD + cs * 8;
        kdst[j] = (w * 4 + j) * 1024;
    }
    #pragma unroll
    for (int j = 0; j < 3; ++j) {
        const int cid = (w * 3 + j) * 64 + l;        // 0..767
        const int d = cid >> 3, cc = cid & 7;
        const int cs = cc ^ (d & 7);
        vsrc[j] = (size_t)d * SEQ + cs * 8;
        vdst[j] = (w * 3 + j) * 1024;
    }

    // Q B-fragments (col = q = lane&31, k(d) = 16*st + 8*lh + e)
    bf16x8 qf[6];
    #pragma unroll
    for (int st = 0; st < 6; ++st)
        qf[st] = *reinterpret_cast<const bf16x8*>(
            &Q[base + (size_t)(q0 + c31) * HD + st * 16 + 8 * lh]);

    f32x16 acc[3] = {};
    f32x16 sA0, sA1, sB0, sB1;
    float l_r = 0.f;
    int vcur = 0, vst = 2;

    auto STAGE = [&](int tile, int kp, int vbuf) {
        const size_t ko = (size_t)tile * 64 * HD;
        #pragma unroll
        for (int j = 0; j < 4; ++j)
            GLDS16(Kg + ko + ksrc[j], (char*)Ks + kp * 16384 + kdst[j]);
        const size_t vo = (size_t)tile * 64;
        #pragma unroll
        for (int j = 0; j < 3; ++j)
            GLDS16(Vg + vo + vsrc[j], (char*)Vs + vbuf * 12288 + vdst[j]);
    };

    auto QKT = [&](int pbuf, f32x16& S0, f32x16& S1) {
        S0 = (f32x16){}; S1 = (f32x16){};
        #pragma unroll
        for (int st = 0; st < 6; ++st) {
            const int slot = (2 * st + lh) ^ (c31 & 7);
            bf16x8 ka0 = *reinterpret_cast<const bf16x8*>(
                (const char*)Ks + pbuf * 16384 + c31 * 256 + slot * 16);
            bf16x8 ka1 = *reinterpret_cast<const bf16x8*>(
                (const char*)Ks + pbuf * 16384 + (32 + c31) * 256 + slot * 16);
            S0 = __builtin_amdgcn_mfma_f32_32x32x16_bf16(ka0, qf[st], S0, 0, 0, 0);
            S1 = __builtin_amdgcn_mfma_f32_32x32x16_bf16(ka1, qf[st], S1, 0, 0, 0);
        }
    };

    auto SMPV = [&](f32x16& S0, f32x16& S1) {
        float p0 = 0.f, p1 = 0.f;
        #pragma unroll
        for (int r = 0; r < 16; ++r) {
            const float e0 = __builtin_amdgcn_exp2f(S0[r]);
            const float e1 = __builtin_amdgcn_exp2f(S1[r]);
            S0[r] = e0; S1[r] = e1; p0 += e0; p1 += e1;
        }
        l_r += p0 + p1;
        unsigned up[2][4][2];
        #pragma unroll
        for (int qd = 0; qd < 4; ++qd)
            #pragma unroll
            for (int j = 0; j < 2; ++j) {
                asm("v_cvt_pk_bf16_f32 %0, %1, %2"
                    : "=v"(up[0][qd][j])
                    : "v"(S0[4 * qd + 2 * j]), "v"(S0[4 * qd + 2 * j + 1]));
                asm("v_cvt_pk_bf16_f32 %0, %1, %2"
                    : "=v"(up[1][qd][j])
                    : "v"(S1[4 * qd + 2 * j]), "v"(S1[4 * qd + 2 * j + 1]));
            }
        const unsigned vbo = vcur * 12288;
        #pragma unroll
        for (int kc = 0; kc < 4; ++kc) {
            const int ks = kc >> 1, cp = kc & 1;
            unsigned x0 = up[ks][2 * cp][0],     x1 = up[ks][2 * cp][1];
            unsigned y0 = up[ks][2 * cp + 1][0], y1 = up[ks][2 * cp + 1][1];
            asm("v_permlane32_swap_b32 %0, %1" : "+v"(x0), "+v"(y0));
            asm("v_permlane32_swap_b32 %0, %1" : "+v"(x1), "+v"(y1));
            u32x4 pw; pw[0] = x0; pw[1] = x1; pw[2] = y0; pw[3] = y1;
            const bf16x8 pa = __builtin_bit_cast(bf16x8, pw);
            __builtin_amdgcn_s_setprio(1);
            #pragma unroll
            for (int dt = 0; dt < 3; ++dt) {
                const int dd = dt * 32 + c31;
                const int slot = (2 * kc + lh) ^ (dd & 7);
                bf16x8 vb = *reinterpret_cast<const bf16x8*>(
                    (const char*)Vs + vbo + dd * 128 + slot * 16);
                acc[dt] = __builtin_amdgcn_mfma_f32_32x32x16_bf16(pa, vb, acc[dt], 0, 0, 0);
            }
            __builtin_amdgcn_s_setprio(0);
        }
        vcur = (vcur == 2) ? 0 : vcur + 1;
        vst  = (vst  == 2) ? 0 : vst  + 1;
    };

    // prologue
    STAGE(0, 0, 0);
    __syncthreads();
    STAGE(1, 1, 1);
    QKT(0, sA0, sA1);

    const int NT = SEQ / 64;   // 64
    if (ord == 0) {
        for (int u2 = 0; u2 < NT / 2; ++u2) {
            const int u = 2 * u2;
            __syncthreads();                       // stage(u+1) drained; PV(u-1) done
            if (u + 2 < NT) STAGE(u + 2, 0, vst);
            QKT(1, sB0, sB1);
            SMPV(sA0, sA1);
            __syncthreads();
            if (u + 3 < NT) STAGE(u + 3, 1, vst);
            if (u + 2 < NT) QKT(0, sA0, sA1);
            SMPV(sB0, sB1);
        }
    } else {
        for (int u2 = 0; u2 < NT / 2; ++u2) {
            const int u = 2 * u2;
            __syncthreads();
            if (u + 2 < NT) STAGE(u + 2, 0, vst);
            SMPV(sA0, sA1);                        // VALU-first: anti-phase with ord==0
            QKT(1, sB0, sB1);
            __syncthreads();
            if (u + 3 < NT) STAGE(u + 3, 1, vst);
            SMPV(sB0, sB1);
            if (u + 2 < NT) QKT(0, sA0, sA1);
        }
    }

    // epilogue: merge l across lane-halves (one permlane), normalize, store
    {
        float ex = l_r;
        asm volatile("" : "+v"(ex));
        asm("v_permlane32_swap_b32 %0, %1" : "+v"(ex), "+v"(l_r));
        l_r += ex;
    }
    const float inv = 1.0f / l_r;
    #pragma unroll
    for (int r = 0; r < 16; ++r) {
        const int ql = (r & 3) + 8 * (r >> 2) + 4 * lh;
        const float ir = __shfl(inv, ql, 64);
        const int q = q0 + ql;
        float* dst = out + ((size_t)(b * SEQ + q)) * DM + hd * HD;
        #pragma unroll
        for (int dt = 0; dt < 3; ++dt)
            dst[dt * 32 + c31] = acc[dt][r] * ir;
    }
}

extern "C" void kernel_launch(void* const* d_in, const int* in_sizes, int n_in,
                              void* d_out, int out_size, void* d_ws, size_t ws_size,
                              hipStream_t stream) {
    const float* hidden = (const float*)d_in[0];
    const float* kv     = (const float*)d_in[1];
    const float* Wq     = (const float*)d_in[2];
    const float* Wk     = (const float*)d_in[3];
    const float* Wv     = (const float*)d_in[4];
    float* out = (float*)d_out;

    // ws layout (bf16): Wt_q, Wt_k, Wt_v, Q, K, Vt  (~41.3 MB total)
    __bf16* Wt_q = (__bf16*)d_ws;
    __bf16* Wt_k = Wt_q + WELEM;
    __bf16* Wt_v = Wt_k + WELEM;
    __bf16* Qb   = Wt_v + WELEM;
    __bf16* Kb   = Qb + XELEM;
    __bf16* Vtb  = Kb + XELEM;

    // converted X lives in d_out (consumed by proj_all, then attn overwrites)
    __bf16* Xh_bf  = (__bf16*)d_out;
    __bf16* Xkv_bf = Xh_bf + XELEM;

    prep<<<6576, 256, 0, stream>>>(hidden, kv, Wq, Wk, Wv,
                                   Xh_bf, Xkv_bf, Wt_q, Wt_k, Wt_v);

    const float qscale = 0.10206207261596575f * 1.4426950408889634f; // 1/sqrt(96)*log2(e)
    proj_all<<<1152, 256, 0, stream>>>(Xh_bf, Xkv_bf, Wt_q, Wt_k, Wt_v,
                                       Qb, Kb, Vtb, qscale);

    attn_kernel<<<512, 256, 0, stream>>>(Qb, Kb, Vtb, out);
}

// Round 15
// 169.307 us; speedup vs baseline: 1.0653x; 1.0419x over previous
//
#include <hip/hip_runtime.h>
#include <hip/hip_bf16.h>

// Multihead cross-attention, B=2, LQ=LK=4096, D=768, H=8, dh=96.
// Pipeline: prep (W transpose + X f32->bf16, one launch) -> fused QKV proj
// (128^2 tile, glds dbuf, XOR-swizzled LDS) -> flash attn (32x32x16,
// 8 waves x 32q in ONE 512-thread block per CU: K/V staged once per CU,
// per-wave-parity phase order for deterministic MFMA/VALU anti-phase,
// cross-tile pipeline, no-max softmax).

typedef __bf16 bf16x8 __attribute__((ext_vector_type(8)));
typedef __bf16 bf16x4 __attribute__((ext_vector_type(4)));
typedef float  f32x4  __attribute__((ext_vector_type(4)));
typedef float  f32x16 __attribute__((ext_vector_type(16)));
typedef unsigned u32x4 __attribute__((ext_vector_type(4)));

#define DM   768
#define NH   8
#define HD   96
#define SEQ  4096
#define BATCH 2
#define WELEM (DM*DM)         // 589824
#define XELEM (BATCH*SEQ*DM)  // 6291456

#define GLDS16(gp, lp) __builtin_amdgcn_global_load_lds( \
    (const __attribute__((address_space(1))) void*)(gp), \
    (__attribute__((address_space(3))) void*)(lp), 16, 0, 0)

// ---------------- prep: X f32->bf16 convert (6144 blocks) + W transpose (432) --
__global__ __launch_bounds__(256) void prep(
    const float* __restrict__ hidden, const float* __restrict__ kv,
    const float* __restrict__ Wq, const float* __restrict__ Wk,
    const float* __restrict__ Wv,
    __bf16* __restrict__ Xh_bf, __bf16* __restrict__ Xkv_bf,
    __bf16* __restrict__ Tq, __bf16* __restrict__ Tk, __bf16* __restrict__ Tv)
{
    __shared__ __bf16 Ls[64][72];   // used by transpose blocks only
    const int id = blockIdx.x;
    const int t = threadIdx.x;

    if (id < 6144) {                // convert: blocks 0..3071 hidden, 3072.. kv
        const int half = id >= 3072;
        const float* X = half ? kv : hidden;
        __bf16* Y      = half ? Xkv_bf : Xh_bf;
        const size_t i = ((size_t)(id - half * 3072) * 256 + t) * 8;
        float4 lo = *reinterpret_cast<const float4*>(X + i);
        float4 hi = *reinterpret_cast<const float4*>(X + i + 4);
        bf16x8 v;
        v[0]=(__bf16)lo.x; v[1]=(__bf16)lo.y; v[2]=(__bf16)lo.z; v[3]=(__bf16)lo.w;
        v[4]=(__bf16)hi.x; v[5]=(__bf16)hi.y; v[6]=(__bf16)hi.z; v[7]=(__bf16)hi.w;
        *reinterpret_cast<bf16x8*>(Y + i) = v;
        return;
    }

    // transpose: 432 blocks = 3 * 144 tiles of 64x64
    const int id2 = id - 6144;
    const int which = id2 / 144;
    const int tile = id2 - which * 144;
    const int ti = tile / 12, tj = tile % 12;
    const float* W = (which == 0) ? Wq : (which == 1) ? Wk : Wv;
    __bf16* T      = (which == 0) ? Tq : (which == 1) ? Tk : Tv;

    const int row = t >> 2, q4 = t & 3;
    const float* src = W + (size_t)(ti * 64 + row) * DM + tj * 64 + q4 * 16;
    float4 f0 = *reinterpret_cast<const float4*>(src);
    float4 f1 = *reinterpret_cast<const float4*>(src + 4);
    float4 f2 = *reinterpret_cast<const float4*>(src + 8);
    float4 f3 = *reinterpret_cast<const float4*>(src + 12);
    bf16x8 v0, v1;
    v0[0]=(__bf16)f0.x; v0[1]=(__bf16)f0.y; v0[2]=(__bf16)f0.z; v0[3]=(__bf16)f0.w;
    v0[4]=(__bf16)f1.x; v0[5]=(__bf16)f1.y; v0[6]=(__bf16)f1.z; v0[7]=(__bf16)f1.w;
    v1[0]=(__bf16)f2.x; v1[1]=(__bf16)f2.y; v1[2]=(__bf16)f2.z; v1[3]=(__bf16)f2.w;
    v1[4]=(__bf16)f3.x; v1[5]=(__bf16)f3.y; v1[6]=(__bf16)f3.z; v1[7]=(__bf16)f3.w;
    *reinterpret_cast<bf16x8*>(&Ls[row][q4 * 16])     = v0;
    *reinterpret_cast<bf16x8*>(&Ls[row][q4 * 16 + 8]) = v1;
    __syncthreads();
    #pragma unroll
    for (int j = 0; j < 2; ++j) {
        const int idx = t + j * 256;
        const int orow = idx >> 3, oc = idx & 7;
        bf16x8 o;
        #pragma unroll
        for (int e = 0; e < 8; ++e) o[e] = Ls[oc * 8 + e][orow];
        *reinterpret_cast<bf16x8*>(
            &T[(size_t)(tj * 64 + orow) * DM + ti * 64 + oc * 8]) = o;
    }
}

// ---------------- fused QKV projection: one launch, 1152 blocks ----------------
__global__ __launch_bounds__(256, 2) void proj_all(
    const __bf16* __restrict__ Xh, const __bf16* __restrict__ Xkv,
    const __bf16* __restrict__ Wtq, const __bf16* __restrict__ Wtk,
    const __bf16* __restrict__ Wtv, __bf16* __restrict__ Yq,
    __bf16* __restrict__ Yk, __bf16* __restrict__ Yv, float qscale)
{
    __shared__ __bf16 As[2][128][64];   // 32 KB
    __shared__ __bf16 Bs[2][128][64];   // 32 KB

    const int t = threadIdx.x;
    const int l = t & 63;
    const int w = t >> 6;
    const int ln = l & 15, g = l >> 4;
    const int wm = w >> 1, wn = w & 1;

    const int id3 = blockIdx.x;
    const int xcd = id3 & 7;
    const int u = id3 >> 3;            // 0..143
    const int which = u % 3;
    const int c = u / 3;               // 0..47
    const int m0 = (xcd * 8 + c / 6) * 128;
    const int n0 = (c % 6) * 128;

    const __bf16* Xb = (which == 0) ? Xh : Xkv;
    const __bf16* Wt = (which == 0) ? Wtq : (which == 1) ? Wtk : Wtv;
    __bf16* Y        = (which == 0) ? Yq : (which == 1) ? Yk : Yv;
    const int mode   = (which == 2) ? 1 : 0;
    const float scale = (which == 0) ? qscale : 1.0f;

    size_t asrc[4], bsrc[4]; unsigned sdst[4];
    #pragma unroll
    for (int j = 0; j < 4; ++j) {
        const int cid = j * 256 + t;              // 0..1023
        const int r = cid >> 3, cc = cid & 7, cs = cc ^ (r & 7);
        asrc[j] = (size_t)(m0 + r) * DM + cs * 8;
        bsrc[j] = (size_t)(n0 + r) * DM + cs * 8;
        sdst[j] = cid * 16;
    }

    f32x4 acc[4][4] = {};

    #pragma unroll
    for (int j = 0; j < 4; ++j) GLDS16(Xb + asrc[j], (char*)As + sdst[j]);
    #pragma unroll
    for (int j = 0; j < 4; ++j) GLDS16(Wt + bsrc[j], (char*)Bs + sdst[j]);
    __syncthreads();

    const int NKT = DM / 64;   // 12
    for (int kt = 0; kt < NKT; ++kt) {
        const int cur = kt & 1;
        if (kt + 1 < NKT) {
            const unsigned nb = (cur ^ 1) * 16384u;
            const size_t k0n = (size_t)(kt + 1) * 64;
            #pragma unroll
            for (int j = 0; j < 4; ++j) GLDS16(Xb + k0n + asrc[j], (char*)As + nb + sdst[j]);
            #pragma unroll
            for (int j = 0; j < 4; ++j) GLDS16(Wt + k0n + bsrc[j], (char*)Bs + nb + sdst[j]);
        }

        #pragma unroll
        for (int kk = 0; kk < 2; ++kk) {
            bf16x8 a[4], b[4];
            #pragma unroll
            for (int ms = 0; ms < 4; ++ms) {
                const int row = wm * 64 + ms * 16 + ln;
                const int slot = (kk * 4 + g) ^ (row & 7);
                a[ms] = *reinterpret_cast<const bf16x8*>(
                    (const char*)As + cur * 16384 + row * 128 + slot * 16);
            }
            #pragma unroll
            for (int ns = 0; ns < 4; ++ns) {
                const int row = wn * 64 + ns * 16 + ln;
                const int slot = (kk * 4 + g) ^ (row & 7);
                b[ns] = *reinterpret_cast<const bf16x8*>(
                    (const char*)Bs + cur * 16384 + row * 128 + slot * 16);
            }
            #pragma unroll
            for (int ms = 0; ms < 4; ++ms)
                #pragma unroll
                for (int ns = 0; ns < 4; ++ns)
                    acc[ms][ns] = __builtin_amdgcn_mfma_f32_16x16x32_bf16(
                        a[ms], b[ns], acc[ms][ns], 0, 0, 0);
        }
        __syncthreads();
    }

    // epilogue: D layout col=ln, row=4g+r  [m89]
    #pragma unroll
    for (int ms = 0; ms < 4; ++ms) {
        #pragma unroll
        for (int ns = 0; ns < 4; ++ns) {
            const int col = n0 + wn * 64 + ns * 16 + ln;
            const int h = col / HD, d = col - h * HD;
            const int row_base = m0 + wm * 64 + ms * 16 + 4 * g;
            if (mode == 0) {
                #pragma unroll
                for (int r = 0; r < 4; ++r) {
                    const int row = row_base + r;
                    const int b_ = row >> 12, q = row & (SEQ - 1);
                    Y[(((size_t)(b_ * NH + h) * SEQ) + q) * HD + d] =
                        (__bf16)(acc[ms][ns][r] * scale);
                }
            } else {
                const int b_ = row_base >> 12, kq = row_base & (SEQ - 1);
                bf16x4 v;
                #pragma unroll
                for (int r = 0; r < 4; ++r) v[r] = (__bf16)acc[ms][ns][r];
                *reinterpret_cast<bf16x4*>(
                    &Y[((size_t)(b_ * NH + h) * HD + d) * SEQ + kq]) = v;
            }
        }
    }
}

// ---------------- flash attention: 512-thread block, 8 waves x 32 q -----------
// 256 blocks (XCD-chunked) = 1 block/CU, 2 waves/SIMD. K/V staged ONCE per CU.
// K dbuf [2][64][128] (XOR r&7), V 3-buf [3][96][64] (XOR d&7).
// p = exp2(s) raw (no-max; constant scale cancels in sum(p*v)/sum(p)).
// Wave parity (w>>2): waves 0-3 {QKT;SMPV}, waves 4-7 {SMPV;QKT} -> each SIMD
// hosts one wave of each parity -> deterministic MFMA/VALU anti-phase.
__global__ __launch_bounds__(512, 2) void attn_kernel(
    const __bf16* __restrict__ Q, const __bf16* __restrict__ K,
    const __bf16* __restrict__ Vt, float* __restrict__ out)
{
    __shared__ __bf16 Ks[2][64][128];  // 32 KB
    __shared__ __bf16 Vs[3][96][64];   // 36 KB

    const int t_ = threadIdx.x;        // 0..511
    const int l = t_ & 63;
    const int w = t_ >> 6;             // 0..7
    const int lh = l >> 5;
    const int c31 = l & 31;
    const int ord = (w >> 2) & 1;      // SIMD w&3 hosts waves w and w+4: anti-phase

    // XCD-chunked swizzle: 256 blocks, XCD x owns bh {2x, 2x+1}
    const int swz = (blockIdx.x & 7) * 32 + (blockIdx.x >> 3);
    const int bh = swz >> 4;           // 0..15
    const int qb = swz & 15;           // 0..15
    const int b = bh >> 3, hd = bh & 7;
    const int q0 = qb * 256 + w * 32;

    const size_t base = (size_t)bh * SEQ * HD;
    const __bf16* Kg = K + base;
    const __bf16* Vg = Vt + base;

    // staging geometry (512 threads): K 1024 chunks in 2 rounds, V 768 chunks
    // in 1.5 rounds (round 1 guarded to waves 0-3). dest = uniform + lane*16.
    size_t ksrc[2], vsrc[2];
    unsigned kdst[2], vdst[2];
    #pragma unroll
    for (int j = 0; j < 2; ++j) {
        const int cid = j * 512 + t_;              // 0..1023
        const int r = cid >> 4, cc = cid & 15;
        int cs = cc ^ (r & 7); if (cs >= 12) cs = 0;
        ksrc[j] = (size_t)r * HD + cs * 8;
        kdst[j] = cid * 16;
        const int vid = j * 512 + t_;              // 0..1023 (valid < 768)
        const int d = vid >> 3, cc2 = vid & 7;
        const int cs2 = cc2 ^ (d & 7);
        vsrc[j] = (size_t)(d < 96 ? d : 0) * SEQ + cs2 * 8;
        vdst[j] = vid * 16;
    }
    const bool vdo2 = t_ < 256;        // round 1: waves 0-3 only (wave-uniform)

    // Q B-fragments (col = q = lane&31, k(d) = 16*st + 8*lh + e)
    bf16x8 qf[6];
    #pragma unroll
    for (int st = 0; st < 6; ++st)
        qf[st] = *reinterpret_cast<const bf16x8*>(
            &Q[base + (size_t)(q0 + c31) * HD + st * 16 + 8 * lh]);

    f32x16 acc[3] = {};
    f32x16 sA0, sA1, sB0, sB1;
    float l_r = 0.f;
    int vcur = 0, vst = 2;

    auto STAGE = [&](int tile, int kp, int vbuf) {
        const size_t ko = (size_t)tile * 64 * HD;
        #pragma unroll
        for (int j = 0; j < 2; ++j)
            GLDS16(Kg + ko + ksrc[j], (char*)Ks + kp * 16384 + kdst[j]);
        const size_t vo = (size_t)tile * 64;
        GLDS16(Vg + vo + vsrc[0], (char*)Vs + vbuf * 12288 + vdst[0]);
        if (vdo2)
            GLDS16(Vg + vo + vsrc[1], (char*)Vs + vbuf * 12288 + vdst[1]);
    };

    auto QKT = [&](int pbuf, f32x16& S0, f32x16& S1) {
        S0 = (f32x16){}; S1 = (f32x16){};
        #pragma unroll
        for (int st = 0; st < 6; ++st) {
            const int slot = (2 * st + lh) ^ (c31 & 7);
            bf16x8 ka0 = *reinterpret_cast<const bf16x8*>(
                (const char*)Ks + pbuf * 16384 + c31 * 256 + slot * 16);
            bf16x8 ka1 = *reinterpret_cast<const bf16x8*>(
                (const char*)Ks + pbuf * 16384 + (32 + c31) * 256 + slot * 16);
            S0 = __builtin_amdgcn_mfma_f32_32x32x16_bf16(ka0, qf[st], S0, 0, 0, 0);
            S1 = __builtin_amdgcn_mfma_f32_32x32x16_bf16(ka1, qf[st], S1, 0, 0, 0);
        }
    };

    auto SMPV = [&](f32x16& S0, f32x16& S1) {
        float p0 = 0.f, p1 = 0.f;
        #pragma unroll
        for (int r = 0; r < 16; ++r) {
            const float e0 = __builtin_amdgcn_exp2f(S0[r]);
            const float e1 = __builtin_amdgcn_exp2f(S1[r]);
            S0[r] = e0; S1[r] = e1; p0 += e0; p1 += e1;
        }
        l_r += p0 + p1;
        unsigned up[2][4][2];
        #pragma unroll
        for (int qd = 0; qd < 4; ++qd)
            #pragma unroll
            for (int j = 0; j < 2; ++j) {
                asm("v_cvt_pk_bf16_f32 %0, %1, %2"
                    : "=v"(up[0][qd][j])
                    : "v"(S0[4 * qd + 2 * j]), "v"(S0[4 * qd + 2 * j + 1]));
                asm("v_cvt_pk_bf16_f32 %0, %1, %2"
                    : "=v"(up[1][qd][j])
                    : "v"(S1[4 * qd + 2 * j]), "v"(S1[4 * qd + 2 * j + 1]));
            }
        const unsigned vbo = vcur * 12288;
        #pragma unroll
        for (int kc = 0; kc < 4; ++kc) {
            const int ks = kc >> 1, cp = kc & 1;
            unsigned x0 = up[ks][2 * cp][0],     x1 = up[ks][2 * cp][1];
            unsigned y0 = up[ks][2 * cp + 1][0], y1 = up[ks][2 * cp + 1][1];
            asm("v_permlane32_swap_b32 %0, %1" : "+v"(x0), "+v"(y0));
            asm("v_permlane32_swap_b32 %0, %1" : "+v"(x1), "+v"(y1));
            u32x4 pw; pw[0] = x0; pw[1] = x1; pw[2] = y0; pw[3] = y1;
            const bf16x8 pa = __builtin_bit_cast(bf16x8, pw);
            __builtin_amdgcn_s_setprio(1);
            #pragma unroll
            for (int dt = 0; dt < 3; ++dt) {
                const int dd = dt * 32 + c31;
                const int slot = (2 * kc + lh) ^ (dd & 7);
                bf16x8 vb = *reinterpret_cast<const bf16x8*>(
                    (const char*)Vs + vbo + dd * 128 + slot * 16);
                acc[dt] = __builtin_amdgcn_mfma_f32_32x32x16_bf16(pa, vb, acc[dt], 0, 0, 0);
            }
            __builtin_amdgcn_s_setprio(0);
        }
        vcur = (vcur == 2) ? 0 : vcur + 1;
        vst  = (vst  == 2) ? 0 : vst  + 1;
    };

    // prologue
    STAGE(0, 0, 0);
    __syncthreads();
    STAGE(1, 1, 1);
    QKT(0, sA0, sA1);

    const int NT = SEQ / 64;   // 64
    if (ord == 0) {
        for (int u2 = 0; u2 < NT / 2; ++u2) {
            const int u = 2 * u2;
            __syncthreads();                       // stage(u+1) drained; PV(u-1) done
            if (u + 2 < NT) STAGE(u + 2, 0, vst);
            QKT(1, sB0, sB1);
            SMPV(sA0, sA1);
            __syncthreads();
            if (u + 3 < NT) STAGE(u + 3, 1, vst);
            if (u + 2 < NT) QKT(0, sA0, sA1);
            SMPV(sB0, sB1);
        }
    } else {
        for (int u2 = 0; u2 < NT / 2; ++u2) {
            const int u = 2 * u2;
            __syncthreads();
            if (u + 2 < NT) STAGE(u + 2, 0, vst);
            SMPV(sA0, sA1);                        // VALU-first: anti-phase partner
            QKT(1, sB0, sB1);
            __syncthreads();
            if (u + 3 < NT) STAGE(u + 3, 1, vst);
            SMPV(sB0, sB1);
            if (u + 2 < NT) QKT(0, sA0, sA1);
        }
    }

    // epilogue: merge l across lane-halves (one permlane), normalize, store
    {
        float ex = l_r;
        asm volatile("" : "+v"(ex));
        asm("v_permlane32_swap_b32 %0, %1" : "+v"(ex), "+v"(l_r));
        l_r += ex;
    }
    const float inv = 1.0f / l_r;
    #pragma unroll
    for (int r = 0; r < 16; ++r) {
        const int ql = (r & 3) + 8 * (r >> 2) + 4 * lh;
        const float ir = __shfl(inv, ql, 64);
        const int q = q0 + ql;
        float* dst = out + ((size_t)(b * SEQ + q)) * DM + hd * HD;
        #pragma unroll
        for (int dt = 0; dt < 3; ++dt)
            dst[dt * 32 + c31] = acc[dt][r] * ir;
    }
}

extern "C" void kernel_launch(void* const* d_in, const int* in_sizes, int n_in,
                              void* d_out, int out_size, void* d_ws, size_t ws_size,
                              hipStream_t stream) {
    const float* hidden = (const float*)d_in[0];
    const float* kv     = (const float*)d_in[1];
    const float* Wq     = (const float*)d_in[2];
    const float* Wk     = (const float*)d_in[3];
    const float* Wv     = (const float*)d_in[4];
    float* out = (float*)d_out;

    // ws layout (bf16): Wt_q, Wt_k, Wt_v, Q, K, Vt  (~41.3 MB total)
    __bf16* Wt_q = (__bf16*)d_ws;
    __bf16* Wt_k = Wt_q + WELEM;
    __bf16* Wt_v = Wt_k + WELEM;
    __bf16* Qb   = Wt_v + WELEM;
    __bf16* Kb   = Qb + XELEM;
    __bf16* Vtb  = Kb + XELEM;

    // converted X lives in d_out (consumed by proj_all, then attn overwrites)
    __bf16* Xh_bf  = (__bf16*)d_out;
    __bf16* Xkv_bf = Xh_bf + XELEM;

    prep<<<6576, 256, 0, stream>>>(hidden, kv, Wq, Wk, Wv,
                                   Xh_bf, Xkv_bf, Wt_q, Wt_k, Wt_v);

    const float qscale = 0.10206207261596575f * 1.4426950408889634f; // 1/sqrt(96)*log2(e)
    proj_all<<<1152, 256, 0, stream>>>(Xh_bf, Xkv_bf, Wt_q, Wt_k, Wt_v,
                                       Qb, Kb, Vtb, qscale);

    attn_kernel<<<256, 512, 0, stream>>>(Qb, Kb, Vtb, out);
}